// Round 4
// baseline (1149.299 us; speedup 1.0000x reference)
//
#include <hip/hip_runtime.h>
#include <hip/hip_bf16.h>
#include <cstdint>
#include <cstddef>

// Problem constants
#define T_DIM 128
#define B_DIM 64
#define E_DIM 1024
#define H_DIM 1024
#define V_DIM 10000
#define L_DIM 2
#define VP2   10240      // V padded to 80 tiles of 128 (= 40 tiles of 256)
#define MROWS 8192       // T*B rows, t-major (row = t*64 + b) = 64 tiles exactly
#define WN    2097152    // L*H*E = 2^21 (per-weight-array element count)
#define WL    1048576    // per-layer weight stride (H*E)

typedef __bf16 bf16_t;
typedef bf16_t bf16x8 __attribute__((ext_vector_type(8)));
typedef bf16_t bf16x4 __attribute__((ext_vector_type(4)));
typedef float  f32x4  __attribute__((ext_vector_type(4)));

__device__ __forceinline__ void g2l16(const void* g, void* l) {
  __builtin_amdgcn_global_load_lds((const __attribute__((address_space(1))) void*)g,
                                   (__attribute__((address_space(3))) void*)l,
                                   16, 0, 0);
}

__device__ __forceinline__ float fast_tanh(float v) {
  v = fminf(15.f, fmaxf(-15.f, v));
  float e = __expf(2.f * v);
  return (e - 1.f) / (e + 1.f);
}

template<int N> __device__ __forceinline__ void waitcnt_vm();
template<> __device__ __forceinline__ void waitcnt_vm<8>() { asm volatile("s_waitcnt vmcnt(8)" ::: "memory"); }
template<> __device__ __forceinline__ void waitcnt_vm<6>() { asm volatile("s_waitcnt vmcnt(6)" ::: "memory"); }
template<> __device__ __forceinline__ void waitcnt_vm<4>() { asm volatile("s_waitcnt vmcnt(4)" ::: "memory"); }
template<> __device__ __forceinline__ void waitcnt_vm<3>() { asm volatile("s_waitcnt vmcnt(3)" ::: "memory"); }
template<> __device__ __forceinline__ void waitcnt_vm<0>() { asm volatile("s_waitcnt vmcnt(0)" ::: "memory"); }

// ---------------------------------------------------------------------------
// gemm256_bt<BM>: C = A @ B^T + bias (+Z two-section) (tanh?) -> outb/outf.
// Tile BM x 256, BK=32, 512 threads (8 waves, 2x4; per-wave BM/2 x 64 out),
// 4-deep LDS ring, prefetch depth 3, counted vmcnt(2*CALLS), single raw
// s_barrier per K-tile, 2 MFMA phases, setprio around MFMA.
//
// LDS layout (per matrix, rows x 64B, NO pad): XOR bank swizzle folded into
// the 128B row-pair: phys 16B-chunk y = ((row&1)<<2 | col16) ^ (row&7),
// addr = (row>>1)*128 + y*16  ->  ds_read_b128 ~2-way (free).  Staging keeps
// the LDS dest LINEAR (global_load_lds constraint) and applies the INVERSE
// permutation to the global source address (within-128B -> same cachelines).
// A+B tile = (BM+256)*4 16B chunks = exactly CALLS=(BM+256)/128 calls of 512.
//
// Z (if set, N==1024): row<64 -> Z[row*1024+n] (HU), else Z[(64+(row&63))*1024+n].
// outb: bf16 full-tile stores.  outf: fp32 at t/b strides, guarded.
// Requires NT=K/32 >= 3, gridDim.x = BMT*BNT with (gridDim.x/BNT)%8==0.
// ---------------------------------------------------------------------------
template<int BM>
__global__ __launch_bounds__(512, 2)
void gemm256_bt(const bf16_t* __restrict__ A, const bf16_t* __restrict__ Bm, int K,
                const float* __restrict__ bias, int Nvalid,
                const float* __restrict__ Z, int do_tanh,
                bf16_t* __restrict__ outb, int outb_stride,
                float* __restrict__ outf, long stride_t, int stride_b, int Mvalid,
                int BNT)
{
  constexpr int ASZ_A = BM * 64;        // bytes per A slot
  constexpr int ASZ_B = 256 * 64;       // bytes per B slot
  constexpr int BUF   = ASZ_A + ASZ_B;  // ring slot
  constexpr int CALLS = (BM + 256) / 128;   // 512-lane g2l16 calls per tile
  constexpr int CA    = 2;              // staging calls issued in phase A
  constexpr int WROWS = BM / 2;         // rows per wave
  constexpr int MI    = WROWS / 16;     // acc rows
  __shared__ alignas(16) char lds[4 * BUF];

  const int tid  = threadIdx.x;
  const int wid  = tid >> 6;
  const int lane = tid & 63;
  const int wr = wid >> 2;          // 0..1
  const int wc = wid & 3;           // 0..3
  const int fr = lane & 15;
  const int fq16 = lane >> 4;       // 16B-chunk index of k-slice (0..3)

  // XCD-stripe swizzle
  int g   = blockIdx.x;
  int SM  = (gridDim.x / BNT) >> 3;
  int xcd = g & 7;
  int q   = g >> 3;
  int bm  = xcd * SM + (q % SM);
  int bn  = q / SM;

  // staging map: chunk c = u*512 + tid; c < BM*4 -> A, else B. LDS dest linear,
  // global source inverse-swizzled within each 128B row-pair.
  const bf16_t* gsrc[CALLS];
  int loff[CALLS];
#pragma unroll
  for (int u = 0; u < CALLS; ++u) {
    int c   = u * 512 + tid;
    int isB = (c >= BM * 4) ? 1 : 0;
    int cm  = isB ? (c - BM * 4) : c;
    int rp  = cm >> 3, y = cm & 7;
    int u3  = y ^ ((rp & 3) << 1);
    int r0  = (u3 >> 2) & 1;
    int row = rp * 2 + r0;
    int col16 = (u3 & 3) ^ r0;
    const bf16_t* base = isB ? (Bm + (size_t)(bn * 256 + row) * K)
                             : (A  + (size_t)(bm * BM  + row) * K);
    gsrc[u] = base + col16 * 8;
    loff[u] = c * 16;
  }

  // swizzled read offsets: addr = (row>>1)*128 + y*16
  int aoff[MI], boff[4];
#pragma unroll
  for (int i = 0; i < MI; ++i) {
    int row = wr * WROWS + i * 16 + fr;
    int y   = (((row & 1) << 2) | fq16) ^ (row & 7);
    aoff[i] = (row >> 1) * 128 + y * 16;
  }
#pragma unroll
  for (int i = 0; i < 4; ++i) {
    int row = wc * 64 + i * 16 + fr;
    int y   = (((row & 1) << 2) | fq16) ^ (row & 7);
    boff[i] = ASZ_A + (row >> 1) * 128 + y * 16;
  }

  f32x4 zero = {0.f, 0.f, 0.f, 0.f};
  f32x4 acc[MI][4];
#pragma unroll
  for (int i = 0; i < MI; ++i)
#pragma unroll
    for (int j = 0; j < 4; ++j) acc[i][j] = zero;

  const int NT = K >> 5;

  // prologue: stage tiles 0,1,2 into slots 0,1,2
#pragma unroll
  for (int u = 0; u < CALLS; ++u) g2l16(gsrc[u],      lds + 0 * BUF + loff[u]);
#pragma unroll
  for (int u = 0; u < CALLS; ++u) g2l16(gsrc[u] + 32, lds + 1 * BUF + loff[u]);
#pragma unroll
  for (int u = 0; u < CALLS; ++u) g2l16(gsrc[u] + 64, lds + 2 * BUF + loff[u]);

  for (int t = 0; t < NT; ++t) {
    if      (t < NT - 2)  waitcnt_vm<2 * CALLS>();
    else if (t == NT - 2) waitcnt_vm<CALLS>();
    else                  waitcnt_vm<0>();
    __builtin_amdgcn_sched_barrier(0);
    __builtin_amdgcn_s_barrier();   // tile-t visible; slot (t+3)%4 free
    asm volatile("" ::: "memory");
    __builtin_amdgcn_sched_barrier(0);

    char* cbuf = lds + (t & 3) * BUF;
    char* sbuf = lds + ((t + 3) & 3) * BUF;
    const int  k3 = (t + 3) << 5;
    const bool st = (t + 3) < NT;

    bf16x8 bfv[4], af[MI / 2];
    // ---- phase A ----
#pragma unroll
    for (int i = 0; i < 4; ++i) bfv[i] = *(const bf16x8*)(cbuf + boff[i]);
#pragma unroll
    for (int i = 0; i < MI / 2; ++i) af[i] = *(const bf16x8*)(cbuf + aoff[i]);
    if (st) {
#pragma unroll
      for (int u = 0; u < CA; ++u) g2l16(gsrc[u] + k3, sbuf + loff[u]);
    }
    asm volatile("s_waitcnt lgkmcnt(0)" ::: "memory");
    __builtin_amdgcn_sched_barrier(0);
    __builtin_amdgcn_s_setprio(1);
#pragma unroll
    for (int mi = 0; mi < MI / 2; ++mi)
#pragma unroll
      for (int ni = 0; ni < 4; ++ni)
        acc[mi][ni] = __builtin_amdgcn_mfma_f32_16x16x32_bf16(af[mi], bfv[ni], acc[mi][ni], 0, 0, 0);
    __builtin_amdgcn_s_setprio(0);

    // ---- phase B ----
#pragma unroll
    for (int i = 0; i < MI / 2; ++i) af[i] = *(const bf16x8*)(cbuf + aoff[MI / 2 + i]);
    if (st) {
#pragma unroll
      for (int u = CA; u < CALLS; ++u) g2l16(gsrc[u] + k3, sbuf + loff[u]);
    }
    asm volatile("s_waitcnt lgkmcnt(0)" ::: "memory");
    __builtin_amdgcn_sched_barrier(0);
    __builtin_amdgcn_s_setprio(1);
#pragma unroll
    for (int mi = 0; mi < MI / 2; ++mi)
#pragma unroll
      for (int ni = 0; ni < 4; ++ni)
        acc[MI / 2 + mi][ni] = __builtin_amdgcn_mfma_f32_16x16x32_bf16(af[mi], bfv[ni], acc[MI / 2 + mi][ni], 0, 0, 0);
    __builtin_amdgcn_s_setprio(0);
  }

  // epilogue: C/D layout col=lane&15, row=(lane>>4)*4+reg (m89-verified)
  const int rb  = (lane >> 4) * 4;
  const int cb_ = lane & 15;
#pragma unroll
  for (int mi = 0; mi < MI; ++mi) {
#pragma unroll
    for (int ni = 0; ni < 4; ++ni) {
      const int col = bn * 256 + wc * 64 + ni * 16 + cb_;
      if (col < Nvalid) {
        const float bv = bias[col];
#pragma unroll
        for (int r = 0; r < 4; ++r) {
          const int row = bm * BM + wr * WROWS + mi * 16 + rb + r;
          float v = acc[mi][ni][r] + bv;
          if (Z) {
            int zr = (row < 64) ? row : 64 + (row & 63);
            v += Z[zr * 1024 + col];
          }
          if (do_tanh) v = fast_tanh(v);
          if (outb) outb[(size_t)row * outb_stride + col] = (bf16_t)v;
          if (outf && row < Mvalid) {
            long o = (long)(row >> 6) * stride_t + (long)(row & 63) * stride_b + col;
            outf[o] = v;
          }
        }
      }
    }
  }
}

// ---------------------------------------------------------------------------
// 128x128 m97-structure GEMM (kept for the small step-0 chain)
// ---------------------------------------------------------------------------
template<int BK>
__global__ __launch_bounds__(256)
void gemm_bt(const bf16_t* __restrict__ A, const bf16_t* __restrict__ Bm, int K,
             const float* __restrict__ bias, int Nvalid,
             const float* __restrict__ Z, int do_tanh,
             bf16_t* __restrict__ outb, int outb_stride,
             float* __restrict__ outf, long stride_t, int stride_b, int Mvalid,
             int BNT, long abatch, long bbatch, long biasbatch, long obatch)
{
  __shared__ alignas(16) bf16_t lA[128 * BK];
  __shared__ alignas(16) bf16_t lB[128 * BK];
  const int tid  = threadIdx.x;
  const int wid  = tid >> 6;
  const int lane = tid & 63;

  int bm, bn;
  if (BNT > 0) {
    int g   = blockIdx.x;
    int SM  = (gridDim.x / BNT) >> 3;
    int xcd = g & 7;
    int q   = g >> 3;
    bm = xcd * SM + (q % SM);
    bn = q / SM;
  } else {
    bn = blockIdx.x;
    bm = 0;
    int batch = blockIdx.y;
    A    += (size_t)batch * abatch;
    Bm   += (size_t)batch * bbatch;
    bias += (size_t)batch * biasbatch;
    if (outf) outf += (size_t)batch * obatch;
  }

  f32x4 zero = {0.f, 0.f, 0.f, 0.f};
  f32x4 acc[4][4];
#pragma unroll
  for (int i = 0; i < 4; ++i)
#pragma unroll
    for (int j = 0; j < 4; ++j) acc[i][j] = zero;

  constexpr int CW    = BK / 8;
  constexpr int CALLS = (128 * BK / 8) / 256;
  const bf16_t* gA[CALLS];
  const bf16_t* gB[CALLS];
  int ldsoff[CALLS];
#pragma unroll
  for (int u = 0; u < CALLS; ++u) {
    int chunk = (u * 4 + wid) * 64 + lane;
    int row = chunk / CW, cc = chunk % CW;
    gA[u] = A  + (size_t)(bm * 128 + row) * K + cc * 8;
    gB[u] = Bm + (size_t)(bn * 128 + row) * K + cc * 8;
    ldsoff[u] = chunk * 16;
  }

  const int mrow = (wid >> 1) * 64;
  const int ncol = (wid & 1) * 64;
  const int fr = lane & 15;
  const int fq = (lane >> 4) * 16;
  char* lAb = (char*)lA;
  char* lBb = (char*)lB;

  for (int k0 = 0; k0 < K; k0 += BK) {
    __syncthreads();
#pragma unroll
    for (int u = 0; u < CALLS; ++u) g2l16(gA[u] + k0, lAb + ldsoff[u]);
#pragma unroll
    for (int u = 0; u < CALLS; ++u) g2l16(gB[u] + k0, lBb + ldsoff[u]);
    __syncthreads();

#pragma unroll
    for (int kk = 0; kk < BK / 32; ++kk) {
      bf16x8 af[4], bfv[4];
#pragma unroll
      for (int t = 0; t < 4; ++t) {
        af[t]  = *(const bf16x8*)(lAb + (mrow + t * 16 + fr) * (2 * BK) + kk * 64 + fq);
        bfv[t] = *(const bf16x8*)(lBb + (ncol + t * 16 + fr) * (2 * BK) + kk * 64 + fq);
      }
#pragma unroll
      for (int tm = 0; tm < 4; ++tm)
#pragma unroll
        for (int tn = 0; tn < 4; ++tn)
          acc[tm][tn] = __builtin_amdgcn_mfma_f32_16x16x32_bf16(af[tm], bfv[tn], acc[tm][tn], 0, 0, 0);
    }
  }

  const int rb = (lane >> 4) * 4;
  const int cb = lane & 15;
#pragma unroll
  for (int tm = 0; tm < 4; ++tm) {
#pragma unroll
    for (int tn = 0; tn < 4; ++tn) {
      const int col = bn * 128 + ncol + tn * 16 + cb;
      const float bv = (col < Nvalid) ? bias[col] : 0.f;
#pragma unroll
      for (int r = 0; r < 4; ++r) {
        const int row = bm * 128 + mrow + tm * 16 + rb + r;
        float v = acc[tm][tn][r] + bv;
        if (Z) {
          int zr = (row < 64) ? row : 64 + (row & 63);
          v += Z[zr * 1024 + col];
        }
        if (do_tanh) v = fast_tanh(v);
        if (outb) outb[(size_t)row * outb_stride + col] = (bf16_t)v;
        if (outf && row < Mvalid && col < Nvalid) {
          long o = (long)(row >> 6) * stride_t + (long)(row & 63) * stride_b + col;
          outf[o] = v;
        }
      }
    }
  }
}

// ---- fused prep: weight cvt x3 + Dw cvt + embedding gather + hidden cvt ----
#define NB_CVT3 6144     // 3*WN/4/256
#define NB_DW   10240    // VP2*1024/4/256
#define NB_GA   8192     // MROWS*1024/4/256
#define NB_HID  256      // L*128*1024/4/256   (was 1024: 4x OOB -> crash)
__global__ void k_prep(const float* __restrict__ Ww, const float* __restrict__ Uw,
                       const float* __restrict__ Fw, bf16_t* __restrict__ Wbf,
                       bf16_t* __restrict__ Ubf, bf16_t* __restrict__ Fbf,
                       const float* __restrict__ Dw, bf16_t* __restrict__ Dbf,
                       const int* __restrict__ inp, const float* __restrict__ etab,
                       bf16_t* __restrict__ Xc,
                       const float* __restrict__ hid, bf16_t* __restrict__ hidb) {
  int b = blockIdx.x;
  bf16x4 o;
  if (b < NB_CVT3) {
    int j = (b * 256 + threadIdx.x) << 2;
    int sel = j >> 21;
    int loc = j & (WN - 1);
    const float* s = (sel == 0) ? Ww : (sel == 1) ? Uw : Fw;
    bf16_t*      d = (sel == 0) ? Wbf : (sel == 1) ? Ubf : Fbf;
    f32x4 v = *(const f32x4*)(s + loc);
#pragma unroll
    for (int k = 0; k < 4; ++k) o[k] = (bf16_t)v[k];
    *(bf16x4*)(d + loc) = o;
  } else if (b < NB_CVT3 + NB_DW) {
    int j = ((b - NB_CVT3) * 256 + threadIdx.x) << 2;
    int r = j >> 10, c = j & 1023;
    f32x4 v = {0.f, 0.f, 0.f, 0.f};
    if (r < V_DIM) v = *(const f32x4*)(Dw + (size_t)r * 1024 + c);
#pragma unroll
    for (int k = 0; k < 4; ++k) o[k] = (bf16_t)v[k];
    *(bf16x4*)(Dbf + j) = o;
  } else if (b < NB_CVT3 + NB_DW + NB_GA) {
    int j = ((b - NB_CVT3 - NB_DW) * 256 + threadIdx.x) << 2;
    int r = j >> 10, e = j & 1023;
    int idx = inp[r];
    f32x4 v = *(const f32x4*)(etab + (size_t)idx * 1024 + e);
#pragma unroll
    for (int k = 0; k < 4; ++k) o[k] = (bf16_t)v[k];
    *(bf16x4*)(Xc + j) = o;
  } else {
    int j = ((b - NB_CVT3 - NB_DW - NB_GA) * 256 + threadIdx.x) << 2;
    int l = j >> 17, r = (j >> 10) & 127, e = j & 1023;
    f32x4 v = {0.f, 0.f, 0.f, 0.f};
    if (r < B_DIM) v = *(const f32x4*)(hid + (size_t)(l * B_DIM + r) * 1024 + e);
#pragma unroll
    for (int k = 0; k < 4; ++k) o[k] = (bf16_t)v[k];
    *(bf16x4*)(hidb + j) = o;
  }
}

extern "C" void kernel_launch(void* const* d_in, const int* in_sizes, int n_in,
                              void* d_out, int out_size, void* d_ws, size_t ws_size,
                              hipStream_t stream) {
  const int*   inp    = (const int*)  d_in[0];
  const float* hidden = (const float*)d_in[1];
  const float* etab   = (const float*)d_in[2];
  const float* Ww     = (const float*)d_in[3];
  const float* Wb     = (const float*)d_in[4];
  const float* Uw     = (const float*)d_in[5];
  const float* Ub     = (const float*)d_in[6];
  const float* Fw     = (const float*)d_in[7];
  const float* Fb     = (const float*)d_in[8];
  const float* Dw     = (const float*)d_in[9];
  const float* Db     = (const float*)d_in[10];
  float* out = (float*)d_out;

  // workspace carve (~66 MB)
  char* p = (char*)d_ws;
  auto carve = [&](size_t n) { char* r = p; p += (n + 255) & ~(size_t)255; return r; };
  bf16_t* Wbf  = (bf16_t*)carve((size_t)WN * 2);
  bf16_t* Ubf  = (bf16_t*)carve((size_t)WN * 2);
  bf16_t* Fbf  = (bf16_t*)carve((size_t)WN * 2);
  bf16_t* Dbf  = (bf16_t*)carve((size_t)VP2 * 1024 * 2);
  bf16_t* Xc   = (bf16_t*)carve((size_t)MROWS * 1024 * 2);
  bf16_t* Hc   = (bf16_t*)carve((size_t)MROWS * 1024 * 2);
  bf16_t* hidb = (bf16_t*)carve((size_t)L_DIM * 128 * 1024 * 2);
  bf16_t* h0b  = (bf16_t*)carve((size_t)128 * 1024 * 2);
  float*  Zbuf = (float*) carve((size_t)2 * 128 * 1024 * 4);  // [l][{HU:64, aU:64}][1024]
  float*  Z0 = Zbuf, * Z1 = Zbuf + 131072;

  float* hall = out + (size_t)T_DIM * B_DIM * V_DIM;
  const long ST_H = (long)L_DIM * B_DIM * H_DIM;   // 131072
  const long ST_V = (long)B_DIM * V_DIM;           // 640000

  // fused prep (one launch)
  k_prep<<<NB_CVT3 + NB_DW + NB_GA + NB_HID, 256, 0, stream>>>(
      Ww, Uw, Fw, Wbf, Ubf, Fbf, Dw, Dbf, inp, etab, Xc, hidden, hidb);

  // step-0 chain (small, BK=64). HU for both layers batched via grid.y.
  gemm_bt<64><<<dim3(8, 2), 256, 0, stream>>>(hidb, Ubf, 1024,
      Ub, 1024, nullptr, 0, nullptr, 0,
      Zbuf, 0L, 1024, 64,
      0, (long)128 * 1024, (long)WL, 1024L, 131072L);

  for (int l = 0; l < L_DIM; ++l) {
    float* Zl = l ? Z1 : Z0;
    // h0_l = tanh(x0 @ Ww^T + Wb + HU_l)
    gemm_bt<64><<<dim3(8, 1), 256, 0, stream>>>(Xc, Wbf + (size_t)l * WL, 1024,
        Wb + l * 1024, 1024, Zl, 1, h0b, 1024,
        nullptr, 0L, 0, 0, 0, 0, 0, 0, 0);
    // aU_l = h0_l @ Uw^T + Ub  -> Z section rows 64..127
    gemm_bt<64><<<dim3(8, 1), 256, 0, stream>>>(h0b, Ubf + (size_t)l * WL, 1024,
        Ub + l * 1024, 1024, nullptr, 0, nullptr, 0,
        Zl + 64 * 1024, 0L, 1024, 64, 0, 0, 0, 0, 0);
    // H = tanh(X @ Ww^T + Wb + Z) -> Hc + hall   (pipelined 128x256 tiles)
    gemm256_bt<128><<<dim3(64 * 4), 512, 0, stream>>>(Xc, Wbf + (size_t)l * WL, 1024,
        Wb + l * 1024, 1024, Zl, 1, Hc, 1024,
        hall + (size_t)l * B_DIM * H_DIM, ST_H, 1024, MROWS, 4);
    // X = tanh(H @ Fw^T + Fb)
    gemm256_bt<128><<<dim3(64 * 4), 512, 0, stream>>>(Hc, Fbf + (size_t)l * WL, 1024,
        Fb + l * 1024, 1024, nullptr, 1, Xc, 1024,
        nullptr, 0L, 0, 0, 4);
  }

  // logits = X @ Dw^T + Db  (256^2 pipelined kernel: 32x40 = 1280 blocks)
  gemm256_bt<256><<<dim3(32 * 40), 512, 0, stream>>>(Xc, Dbf, 1024,
      Db, V_DIM, nullptr, 0, nullptr, 0,
      out, ST_V, V_DIM, MROWS, 40);

  (void)in_sizes; (void)n_in; (void)out_size; (void)ws_size;
}

// Round 5
// 1013.887 us; speedup vs baseline: 1.1336x; 1.1336x over previous
//
#include <hip/hip_runtime.h>
#include <hip/hip_bf16.h>
#include <cstdint>
#include <cstddef>

// Problem constants
#define T_DIM 128
#define B_DIM 64
#define E_DIM 1024
#define H_DIM 1024
#define V_DIM 10000
#define L_DIM 2
#define VP2   10240      // V padded to 80 tiles of 128 (= 40 tiles of 256)
#define MROWS 8192       // T*B rows, t-major (row = t*64 + b) = 64 tiles exactly
#define WN    2097152    // L*H*E = 2^21 (per-weight-array element count)
#define WL    1048576    // per-layer weight stride (H*E)

typedef __bf16 bf16_t;
typedef bf16_t bf16x8 __attribute__((ext_vector_type(8)));
typedef bf16_t bf16x4 __attribute__((ext_vector_type(4)));
typedef float  f32x4  __attribute__((ext_vector_type(4)));

__device__ __forceinline__ void g2l16(const void* g, void* l) {
  __builtin_amdgcn_global_load_lds((const __attribute__((address_space(1))) void*)g,
                                   (__attribute__((address_space(3))) void*)l,
                                   16, 0, 0);
}

__device__ __forceinline__ float fast_tanh(float v) {
  v = fminf(15.f, fmaxf(-15.f, v));
  float e = __expf(2.f * v);
  return (e - 1.f) / (e + 1.f);
}

template<int N> __device__ __forceinline__ void waitcnt_vm();
template<> __device__ __forceinline__ void waitcnt_vm<8>() { asm volatile("s_waitcnt vmcnt(8)" ::: "memory"); }
template<> __device__ __forceinline__ void waitcnt_vm<6>() { asm volatile("s_waitcnt vmcnt(6)" ::: "memory"); }
template<> __device__ __forceinline__ void waitcnt_vm<4>() { asm volatile("s_waitcnt vmcnt(4)" ::: "memory"); }
template<> __device__ __forceinline__ void waitcnt_vm<3>() { asm volatile("s_waitcnt vmcnt(3)" ::: "memory"); }
template<> __device__ __forceinline__ void waitcnt_vm<0>() { asm volatile("s_waitcnt vmcnt(0)" ::: "memory"); }

// ---------------------------------------------------------------------------
// gemm256_bt<BM>: C = A @ B^T + bias (+Z two-section) (tanh?) -> outb/outf.
// Tile BM x 256, BK=32, 512 threads (8 waves, 2x4; per-wave BM/2 x 64 out),
// 4-deep LDS ring, prefetch depth 3, counted vmcnt(2*CALLS), single raw
// s_barrier per K-tile, 2 MFMA phases, setprio around MFMA.
// NOTE (r4 post-mortem): only use where grid >= 2 rounds of CUs or the
// dispatch is large; at 256-block single-round grids the 1-block/CU
// occupancy exposes all pipeline bubbles and loses to gemm_bt's TLP.
//
// LDS layout (per matrix, rows x 64B, NO pad): XOR bank swizzle folded into
// the 128B row-pair: phys 16B-chunk y = ((row&1)<<2 | col16) ^ (row&7),
// addr = (row>>1)*128 + y*16  ->  ds_read_b128 ~2-way (free).  Staging keeps
// the LDS dest LINEAR (global_load_lds constraint) and applies the INVERSE
// permutation to the global source address (within-128B -> same cachelines).
// A+B tile = (BM+256)*4 16B chunks = exactly CALLS=(BM+256)/128 calls of 512.
// ---------------------------------------------------------------------------
template<int BM>
__global__ __launch_bounds__(512, 2)
void gemm256_bt(const bf16_t* __restrict__ A, const bf16_t* __restrict__ Bm, int K,
                const float* __restrict__ bias, int Nvalid,
                const float* __restrict__ Z, int do_tanh,
                bf16_t* __restrict__ outb, int outb_stride,
                float* __restrict__ outf, long stride_t, int stride_b, int Mvalid,
                int BNT)
{
  constexpr int ASZ_A = BM * 64;        // bytes per A slot
  constexpr int ASZ_B = 256 * 64;       // bytes per B slot
  constexpr int BUF   = ASZ_A + ASZ_B;  // ring slot
  constexpr int CALLS = (BM + 256) / 128;   // 512-lane g2l16 calls per tile
  constexpr int CA    = 2;              // staging calls issued in phase A
  constexpr int WROWS = BM / 2;         // rows per wave
  constexpr int MI    = WROWS / 16;     // acc rows
  __shared__ alignas(16) char lds[4 * BUF];

  const int tid  = threadIdx.x;
  const int wid  = tid >> 6;
  const int lane = tid & 63;
  const int wr = wid >> 2;          // 0..1
  const int wc = wid & 3;           // 0..3
  const int fr = lane & 15;
  const int fq16 = lane >> 4;       // 16B-chunk index of k-slice (0..3)

  // XCD-stripe swizzle
  int g   = blockIdx.x;
  int SM  = (gridDim.x / BNT) >> 3;
  int xcd = g & 7;
  int q   = g >> 3;
  int bm  = xcd * SM + (q % SM);
  int bn  = q / SM;

  // staging map: chunk c = u*512 + tid; c < BM*4 -> A, else B. LDS dest linear,
  // global source inverse-swizzled within each 128B row-pair.
  const bf16_t* gsrc[CALLS];
  int loff[CALLS];
#pragma unroll
  for (int u = 0; u < CALLS; ++u) {
    int c   = u * 512 + tid;
    int isB = (c >= BM * 4) ? 1 : 0;
    int cm  = isB ? (c - BM * 4) : c;
    int rp  = cm >> 3, y = cm & 7;
    int u3  = y ^ ((rp & 3) << 1);
    int r0  = (u3 >> 2) & 1;
    int row = rp * 2 + r0;
    int col16 = (u3 & 3) ^ r0;
    const bf16_t* base = isB ? (Bm + (size_t)(bn * 256 + row) * K)
                             : (A  + (size_t)(bm * BM  + row) * K);
    gsrc[u] = base + col16 * 8;
    loff[u] = c * 16;
  }

  // swizzled read offsets: addr = (row>>1)*128 + y*16
  int aoff[MI], boff[4];
#pragma unroll
  for (int i = 0; i < MI; ++i) {
    int row = wr * WROWS + i * 16 + fr;
    int y   = (((row & 1) << 2) | fq16) ^ (row & 7);
    aoff[i] = (row >> 1) * 128 + y * 16;
  }
#pragma unroll
  for (int i = 0; i < 4; ++i) {
    int row = wc * 64 + i * 16 + fr;
    int y   = (((row & 1) << 2) | fq16) ^ (row & 7);
    boff[i] = ASZ_A + (row >> 1) * 128 + y * 16;
  }

  f32x4 zero = {0.f, 0.f, 0.f, 0.f};
  f32x4 acc[MI][4];
#pragma unroll
  for (int i = 0; i < MI; ++i)
#pragma unroll
    for (int j = 0; j < 4; ++j) acc[i][j] = zero;

  const int NT = K >> 5;

  // prologue: stage tiles 0,1,2 into slots 0,1,2
#pragma unroll
  for (int u = 0; u < CALLS; ++u) g2l16(gsrc[u],      lds + 0 * BUF + loff[u]);
#pragma unroll
  for (int u = 0; u < CALLS; ++u) g2l16(gsrc[u] + 32, lds + 1 * BUF + loff[u]);
#pragma unroll
  for (int u = 0; u < CALLS; ++u) g2l16(gsrc[u] + 64, lds + 2 * BUF + loff[u]);

  for (int t = 0; t < NT; ++t) {
    if      (t < NT - 2)  waitcnt_vm<2 * CALLS>();
    else if (t == NT - 2) waitcnt_vm<CALLS>();
    else                  waitcnt_vm<0>();
    __builtin_amdgcn_sched_barrier(0);
    __builtin_amdgcn_s_barrier();   // tile-t visible; slot (t+3)%4 free
    asm volatile("" ::: "memory");
    __builtin_amdgcn_sched_barrier(0);

    char* cbuf = lds + (t & 3) * BUF;
    char* sbuf = lds + ((t + 3) & 3) * BUF;
    const int  k3 = (t + 3) << 5;
    const bool st = (t + 3) < NT;

    bf16x8 bfv[4], af[MI / 2];
    // ---- phase A ----
#pragma unroll
    for (int i = 0; i < 4; ++i) bfv[i] = *(const bf16x8*)(cbuf + boff[i]);
#pragma unroll
    for (int i = 0; i < MI / 2; ++i) af[i] = *(const bf16x8*)(cbuf + aoff[i]);
    if (st) {
#pragma unroll
      for (int u = 0; u < CA; ++u) g2l16(gsrc[u] + k3, sbuf + loff[u]);
    }
    asm volatile("s_waitcnt lgkmcnt(0)" ::: "memory");
    __builtin_amdgcn_sched_barrier(0);
    __builtin_amdgcn_s_setprio(1);
#pragma unroll
    for (int mi = 0; mi < MI / 2; ++mi)
#pragma unroll
      for (int ni = 0; ni < 4; ++ni)
        acc[mi][ni] = __builtin_amdgcn_mfma_f32_16x16x32_bf16(af[mi], bfv[ni], acc[mi][ni], 0, 0, 0);
    __builtin_amdgcn_s_setprio(0);

    // ---- phase B ----
#pragma unroll
    for (int i = 0; i < MI / 2; ++i) af[i] = *(const bf16x8*)(cbuf + aoff[MI / 2 + i]);
    if (st) {
#pragma unroll
      for (int u = CA; u < CALLS; ++u) g2l16(gsrc[u] + k3, sbuf + loff[u]);
    }
    asm volatile("s_waitcnt lgkmcnt(0)" ::: "memory");
    __builtin_amdgcn_sched_barrier(0);
    __builtin_amdgcn_s_setprio(1);
#pragma unroll
    for (int mi = 0; mi < MI / 2; ++mi)
#pragma unroll
      for (int ni = 0; ni < 4; ++ni)
        acc[MI / 2 + mi][ni] = __builtin_amdgcn_mfma_f32_16x16x32_bf16(af[mi], bfv[ni], acc[MI / 2 + mi][ni], 0, 0, 0);
    __builtin_amdgcn_s_setprio(0);
  }

  // epilogue: C/D layout col=lane&15, row=(lane>>4)*4+reg (m89-verified)
  const int rb  = (lane >> 4) * 4;
  const int cb_ = lane & 15;
#pragma unroll
  for (int mi = 0; mi < MI; ++mi) {
#pragma unroll
    for (int ni = 0; ni < 4; ++ni) {
      const int col = bn * 256 + wc * 64 + ni * 16 + cb_;
      if (col < Nvalid) {
        const float bv = bias[col];
#pragma unroll
        for (int r = 0; r < 4; ++r) {
          const int row = bm * BM + wr * WROWS + mi * 16 + rb + r;
          float v = acc[mi][ni][r] + bv;
          if (Z) {
            int zr = (row < 64) ? row : 64 + (row & 63);
            v += Z[zr * 1024 + col];
          }
          if (do_tanh) v = fast_tanh(v);
          if (outb) outb[(size_t)row * outb_stride + col] = (bf16_t)v;
          if (outf && row < Mvalid) {
            long o = (long)(row >> 6) * stride_t + (long)(row & 63) * stride_b + col;
            outf[o] = v;
          }
        }
      }
    }
  }
}

// ---------------------------------------------------------------------------
// 128x128 m97-structure GEMM (per-layer + step-0 chains; high-TLP regime)
// ---------------------------------------------------------------------------
template<int BK>
__global__ __launch_bounds__(256)
void gemm_bt(const bf16_t* __restrict__ A, const bf16_t* __restrict__ Bm, int K,
             const float* __restrict__ bias, int Nvalid,
             const float* __restrict__ Z, int do_tanh,
             bf16_t* __restrict__ outb, int outb_stride,
             float* __restrict__ outf, long stride_t, int stride_b, int Mvalid,
             int BNT, long abatch, long bbatch, long biasbatch, long obatch)
{
  __shared__ alignas(16) bf16_t lA[128 * BK];
  __shared__ alignas(16) bf16_t lB[128 * BK];
  const int tid  = threadIdx.x;
  const int wid  = tid >> 6;
  const int lane = tid & 63;

  int bm, bn;
  if (BNT > 0) {
    int g   = blockIdx.x;
    int SM  = (gridDim.x / BNT) >> 3;
    int xcd = g & 7;
    int q   = g >> 3;
    bm = xcd * SM + (q % SM);
    bn = q / SM;
  } else {
    bn = blockIdx.x;
    bm = 0;
    int batch = blockIdx.y;
    A    += (size_t)batch * abatch;
    Bm   += (size_t)batch * bbatch;
    bias += (size_t)batch * biasbatch;
    if (outf) outf += (size_t)batch * obatch;
  }

  f32x4 zero = {0.f, 0.f, 0.f, 0.f};
  f32x4 acc[4][4];
#pragma unroll
  for (int i = 0; i < 4; ++i)
#pragma unroll
    for (int j = 0; j < 4; ++j) acc[i][j] = zero;

  constexpr int CW    = BK / 8;
  constexpr int CALLS = (128 * BK / 8) / 256;
  const bf16_t* gA[CALLS];
  const bf16_t* gB[CALLS];
  int ldsoff[CALLS];
#pragma unroll
  for (int u = 0; u < CALLS; ++u) {
    int chunk = (u * 4 + wid) * 64 + lane;
    int row = chunk / CW, cc = chunk % CW;
    gA[u] = A  + (size_t)(bm * 128 + row) * K + cc * 8;
    gB[u] = Bm + (size_t)(bn * 128 + row) * K + cc * 8;
    ldsoff[u] = chunk * 16;
  }

  const int mrow = (wid >> 1) * 64;
  const int ncol = (wid & 1) * 64;
  const int fr = lane & 15;
  const int fq = (lane >> 4) * 16;
  char* lAb = (char*)lA;
  char* lBb = (char*)lB;

  for (int k0 = 0; k0 < K; k0 += BK) {
    __syncthreads();
#pragma unroll
    for (int u = 0; u < CALLS; ++u) g2l16(gA[u] + k0, lAb + ldsoff[u]);
#pragma unroll
    for (int u = 0; u < CALLS; ++u) g2l16(gB[u] + k0, lBb + ldsoff[u]);
    __syncthreads();

#pragma unroll
    for (int kk = 0; kk < BK / 32; ++kk) {
      bf16x8 af[4], bfv[4];
#pragma unroll
      for (int t = 0; t < 4; ++t) {
        af[t]  = *(const bf16x8*)(lAb + (mrow + t * 16 + fr) * (2 * BK) + kk * 64 + fq);
        bfv[t] = *(const bf16x8*)(lBb + (ncol + t * 16 + fr) * (2 * BK) + kk * 64 + fq);
      }
#pragma unroll
      for (int tm = 0; tm < 4; ++tm)
#pragma unroll
        for (int tn = 0; tn < 4; ++tn)
          acc[tm][tn] = __builtin_amdgcn_mfma_f32_16x16x32_bf16(af[tm], bfv[tn], acc[tm][tn], 0, 0, 0);
    }
  }

  const int rb = (lane >> 4) * 4;
  const int cb = lane & 15;
#pragma unroll
  for (int tm = 0; tm < 4; ++tm) {
#pragma unroll
    for (int tn = 0; tn < 4; ++tn) {
      const int col = bn * 128 + ncol + tn * 16 + cb;
      const float bv = (col < Nvalid) ? bias[col] : 0.f;
#pragma unroll
      for (int r = 0; r < 4; ++r) {
        const int row = bm * 128 + mrow + tm * 16 + rb + r;
        float v = acc[tm][tn][r] + bv;
        if (Z) {
          int zr = (row < 64) ? row : 64 + (row & 63);
          v += Z[zr * 1024 + col];
        }
        if (do_tanh) v = fast_tanh(v);
        if (outb) outb[(size_t)row * outb_stride + col] = (bf16_t)v;
        if (outf && row < Mvalid && col < Nvalid) {
          long o = (long)(row >> 6) * stride_t + (long)(row & 63) * stride_b + col;
          outf[o] = v;
        }
      }
    }
  }
}

// ---- fused prep: weight cvt x3 + Dw cvt + embedding gather + hidden cvt ----
#define NB_CVT3 6144     // 3*WN/4/256
#define NB_DW   10240    // VP2*1024/4/256
#define NB_GA   8192     // MROWS*1024/4/256
#define NB_HID  256      // L*128*1024/4/256
__global__ void k_prep(const float* __restrict__ Ww, const float* __restrict__ Uw,
                       const float* __restrict__ Fw, bf16_t* __restrict__ Wbf,
                       bf16_t* __restrict__ Ubf, bf16_t* __restrict__ Fbf,
                       const float* __restrict__ Dw, bf16_t* __restrict__ Dbf,
                       const int* __restrict__ inp, const float* __restrict__ etab,
                       bf16_t* __restrict__ Xc,
                       const float* __restrict__ hid, bf16_t* __restrict__ hidb) {
  int b = blockIdx.x;
  bf16x4 o;
  if (b < NB_CVT3) {
    int j = (b * 256 + threadIdx.x) << 2;
    int sel = j >> 21;
    int loc = j & (WN - 1);
    const float* s = (sel == 0) ? Ww : (sel == 1) ? Uw : Fw;
    bf16_t*      d = (sel == 0) ? Wbf : (sel == 1) ? Ubf : Fbf;
    f32x4 v = *(const f32x4*)(s + loc);
#pragma unroll
    for (int k = 0; k < 4; ++k) o[k] = (bf16_t)v[k];
    *(bf16x4*)(d + loc) = o;
  } else if (b < NB_CVT3 + NB_DW) {
    int j = ((b - NB_CVT3) * 256 + threadIdx.x) << 2;
    int r = j >> 10, c = j & 1023;
    f32x4 v = {0.f, 0.f, 0.f, 0.f};
    if (r < V_DIM) v = *(const f32x4*)(Dw + (size_t)r * 1024 + c);
#pragma unroll
    for (int k = 0; k < 4; ++k) o[k] = (bf16_t)v[k];
    *(bf16x4*)(Dbf + j) = o;
  } else if (b < NB_CVT3 + NB_DW + NB_GA) {
    int j = ((b - NB_CVT3 - NB_DW) * 256 + threadIdx.x) << 2;
    int r = j >> 10, e = j & 1023;
    int idx = inp[r];
    f32x4 v = *(const f32x4*)(etab + (size_t)idx * 1024 + e);
#pragma unroll
    for (int k = 0; k < 4; ++k) o[k] = (bf16_t)v[k];
    *(bf16x4*)(Xc + j) = o;
  } else {
    int j = ((b - NB_CVT3 - NB_DW - NB_GA) * 256 + threadIdx.x) << 2;
    int l = j >> 17, r = (j >> 10) & 127, e = j & 1023;
    f32x4 v = {0.f, 0.f, 0.f, 0.f};
    if (r < B_DIM) v = *(const f32x4*)(hid + (size_t)(l * B_DIM + r) * 1024 + e);
#pragma unroll
    for (int k = 0; k < 4; ++k) o[k] = (bf16_t)v[k];
    *(bf16x4*)(hidb + j) = o;
  }
}

extern "C" void kernel_launch(void* const* d_in, const int* in_sizes, int n_in,
                              void* d_out, int out_size, void* d_ws, size_t ws_size,
                              hipStream_t stream) {
  const int*   inp    = (const int*)  d_in[0];
  const float* hidden = (const float*)d_in[1];
  const float* etab   = (const float*)d_in[2];
  const float* Ww     = (const float*)d_in[3];
  const float* Wb     = (const float*)d_in[4];
  const float* Uw     = (const float*)d_in[5];
  const float* Ub     = (const float*)d_in[6];
  const float* Fw     = (const float*)d_in[7];
  const float* Fb     = (const float*)d_in[8];
  const float* Dw     = (const float*)d_in[9];
  const float* Db     = (const float*)d_in[10];
  float* out = (float*)d_out;

  // workspace carve (~66 MB)
  char* p = (char*)d_ws;
  auto carve = [&](size_t n) { char* r = p; p += (n + 255) & ~(size_t)255; return r; };
  bf16_t* Wbf  = (bf16_t*)carve((size_t)WN * 2);
  bf16_t* Ubf  = (bf16_t*)carve((size_t)WN * 2);
  bf16_t* Fbf  = (bf16_t*)carve((size_t)WN * 2);
  bf16_t* Dbf  = (bf16_t*)carve((size_t)VP2 * 1024 * 2);
  bf16_t* Xc   = (bf16_t*)carve((size_t)MROWS * 1024 * 2);
  bf16_t* Hc   = (bf16_t*)carve((size_t)MROWS * 1024 * 2);
  bf16_t* hidb = (bf16_t*)carve((size_t)L_DIM * 128 * 1024 * 2);
  bf16_t* h0b  = (bf16_t*)carve((size_t)128 * 1024 * 2);
  float*  Zbuf = (float*) carve((size_t)2 * 128 * 1024 * 4);  // [l][{HU:64, aU:64}][1024]
  float*  Z0 = Zbuf, * Z1 = Zbuf + 131072;

  float* hall = out + (size_t)T_DIM * B_DIM * V_DIM;
  const long ST_H = (long)L_DIM * B_DIM * H_DIM;   // 131072
  const long ST_V = (long)B_DIM * V_DIM;           // 640000

  // fused prep (one launch)
  k_prep<<<NB_CVT3 + NB_DW + NB_GA + NB_HID, 256, 0, stream>>>(
      Ww, Uw, Fw, Wbf, Ubf, Fbf, Dw, Dbf, inp, etab, Xc, hidden, hidb);

  // step-0 chain (small, BK=64). HU for both layers batched via grid.y.
  gemm_bt<64><<<dim3(8, 2), 256, 0, stream>>>(hidb, Ubf, 1024,
      Ub, 1024, nullptr, 0, nullptr, 0,
      Zbuf, 0L, 1024, 64,
      0, (long)128 * 1024, (long)WL, 1024L, 131072L);

  for (int l = 0; l < L_DIM; ++l) {
    float* Zl = l ? Z1 : Z0;
    // h0_l = tanh(x0 @ Ww^T + Wb + HU_l)
    gemm_bt<64><<<dim3(8, 1), 256, 0, stream>>>(Xc, Wbf + (size_t)l * WL, 1024,
        Wb + l * 1024, 1024, Zl, 1, h0b, 1024,
        nullptr, 0L, 0, 0, 0, 0, 0, 0, 0);
    // aU_l = h0_l @ Uw^T + Ub  -> Z section rows 64..127
    gemm_bt<64><<<dim3(8, 1), 256, 0, stream>>>(h0b, Ubf + (size_t)l * WL, 1024,
        Ub + l * 1024, 1024, nullptr, 0, nullptr, 0,
        Zl + 64 * 1024, 0L, 1024, 64, 0, 0, 0, 0, 0);
    // H = tanh(X @ Ww^T + Wb + Z) -> Hc + hall   (m97 structure, 512 blocks)
    gemm_bt<32><<<dim3(64 * 8), 256, 0, stream>>>(Xc, Wbf + (size_t)l * WL, 1024,
        Wb + l * 1024, 1024, Zl, 1, Hc, 1024,
        hall + (size_t)l * B_DIM * H_DIM, ST_H, 1024, MROWS,
        8, 0, 0, 0, 0);
    // X = tanh(H @ Fw^T + Fb)
    gemm_bt<32><<<dim3(64 * 8), 256, 0, stream>>>(Hc, Fbf + (size_t)l * WL, 1024,
        Fb + l * 1024, 1024, nullptr, 1, Xc, 1024,
        nullptr, 0L, 0, 0, 8, 0, 0, 0, 0);
  }

  // logits = X @ Dw^T + Db  (256^2 pipelined kernel: 32x40 = 1280 blocks)
  gemm256_bt<256><<<dim3(32 * 40), 512, 0, stream>>>(Xc, Dbf, 1024,
      Db, V_DIM, nullptr, 0, nullptr, 0,
      out, ST_V, V_DIM, MROWS, 40);

  (void)in_sizes; (void)n_in; (void)out_size; (void)ws_size;
}